// Round 1
// baseline (74.311 us; speedup 1.0000x reference)
//
#include <hip/hip_runtime.h>
#include <math.h>

#define NVERT 289
#define NFACE 512
#define MAXB 128   // max binned faces per 8x8 tile (analysis: ~10-16 typical)

// Decode face f -> vertex indices (matches _build_faces ordering).
__device__ __forceinline__ void face_verts(int f, int& v0, int& v1, int& v2) {
    int g = f >> 6, i = f & 63, rr = i >> 3, cc = i & 7;
    int ny = 2 * rr + (g >> 2);
    int oddx = ((g & 2) ? 0 : 1) ^ (g >> 2);
    int nx = 2 * cc + oddx;
    int p = g & 3;
    const int dy0[4] = {0, 0, 0, 1};
    const int dy1[4] = {0, 1, 0, 0};
    const int dx2[4] = {0, 1, 1, 0};
    v0 = (ny + dy0[p]) * 17 + nx + 1;
    v1 = (ny + dy1[p]) * 17 + nx;
    v2 = (ny + 1) * 17 + nx + dx2[p];
}

// 256 blocks: one 8x8-pixel tile per CU. 256 threads: 4 slices x 64 pixels.
// Phase 4 redesigned: merge emits selection codes + zmax (two-pass softmax,
// matching the reference), then ALL 256 threads shade (2 faces each) so the
// scattered texture gathers are issued from 4 waves instead of 1.
__global__ __launch_bounds__(256) void nvp_kernel(
    const float* __restrict__ xy_off,
    const float* __restrict__ z_grid,
    const float* __restrict__ texd,
    const float* __restrict__ R_in,
    const float* __restrict__ T_in,
    const float* __restrict__ R_out,
    const float* __restrict__ T_out,
    float* __restrict__ out)
{
    __shared__ __align__(16) float s_f[MAXB * 28];
    __shared__ float s_vx[NVERT], s_vy[NVERT], s_vz[NVERT];
    __shared__ unsigned char s_flag[NFACE];
    __shared__ int s_list[MAXB];
    __shared__ int s_nf;
    __shared__ float s_tz[4][64][9];
    __shared__ float s_td[4][64][9];
    __shared__ int   s_ti[4][64][9];
    __shared__ int   s_sel[64][9];   // merged top-8 selection codes (pad->9)
    __shared__ float s_zmax[64];     // per-pixel softmax max (zinv space)
    __shared__ float s_pS[4][64], s_pR[4][64], s_pG[4][64];
    __shared__ float s_pB[4][64], s_pD[4][64], s_pO[4][64];

    const int tid = threadIdx.x;
    const int tileX = blockIdx.x & 15;
    const int tileY = blockIdx.x >> 4;

    const float SC = 0.57735026918962576f;        // tan(30 deg)
    const float SI = 1.0f / 0.57735026918962576f; // 1/SCALE

    // ---------------- Phase 0: screen-space vertices ----------------
    for (int v = tid; v < NVERT; v += 256) {
        int ix = v % 17, iy = v / 17;
        float gx = -1.0f + 0.125f * (float)ix;
        float gy = -1.0f + 0.125f * (float)iy;
        float sx = (gx + xy_off[2 * v]) * SC;
        float sy = (gy + xy_off[2 * v + 1]) * SC;
        float z = z_grid[v];
        float X = sx * z, Y = sy * z, Z = z;
        float p0 = X - T_in[0], p1 = Y - T_in[1], p2 = Z - T_in[2];
        float wxx = R_in[0] * p0 + R_in[1] * p1 + R_in[2] * p2;
        float wyy = R_in[3] * p0 + R_in[4] * p1 + R_in[5] * p2;
        float wzz = R_in[6] * p0 + R_in[7] * p1 + R_in[8] * p2;
        float vx = wxx * R_out[0] + wyy * R_out[3] + wzz * R_out[6] + T_out[0];
        float vy = wxx * R_out[1] + wyy * R_out[4] + wzz * R_out[7] + T_out[1];
        float vz = wxx * R_out[2] + wyy * R_out[5] + wzz * R_out[8] + T_out[2];
        float zden = (vz >= 0.0f) ? fmaxf(vz, 0.01f) : fminf(vz, -0.01f);
        s_vx[v] = SI * vx / zden;
        s_vy[v] = SI * vy / zden;
        s_vz[v] = vz;
    }
    __syncthreads();

    // tile NDC bounds (px decreasing in x, py decreasing in y); 8px tile
    const float pxmax = 1.0f - ((float)(tileX * 8) + 0.5f) * (1.0f / 64.0f);
    const float pxmin = 1.0f - ((float)(tileX * 8) + 7.5f) * (1.0f / 64.0f);
    const float pymax = 1.0f - ((float)(tileY * 8) + 0.5f) * (1.0f / 64.0f);
    const float pymin = 1.0f - ((float)(tileY * 8) + 7.5f) * (1.0f / 64.0f);
    const float MARG = 0.015f;  // validity needs edge-dist < 0.01 NDC

    // ---------------- Phase 1a: cheap bbox flags only ----------------
    for (int f = tid; f < NFACE; f += 256) {
        int v0, v1, v2;
        face_verts(f, v0, v1, v2);
        float ax = s_vx[v0], ay = s_vy[v0];
        float bx = s_vx[v1], by = s_vy[v1];
        float cx = s_vx[v2], cy = s_vy[v2];
        float minx = fminf(ax, fminf(bx, cx)), maxx = fmaxf(ax, fmaxf(bx, cx));
        float miny = fminf(ay, fminf(by, cy)), maxy = fmaxf(ay, fmaxf(by, cy));
        bool ov = (minx - MARG <= pxmax) && (maxx + MARG >= pxmin) &&
                  (miny - MARG <= pymax) && (maxy + MARG >= pymin);
        s_flag[f] = ov ? 1 : 0;
    }
    __syncthreads();

    // ---------------- Phase 2: ordered compaction (wave 0) ----------------
    if (tid < 64) {
        int cnt = 0;
        for (int base = 0; base < NFACE; base += 64) {
            bool ov = s_flag[base + tid] != 0;
            unsigned long long mask = __ballot(ov);
            if (ov) {
                int pos = cnt + (int)__popcll(mask & ((1ull << tid) - 1ull));
                if (pos < MAXB) s_list[pos] = base + tid;
            }
            cnt += (int)__popcll(mask);
        }
        if (tid == 0) s_nf = (cnt < MAXB) ? cnt : MAXB;
    }
    __syncthreads();

    const int nf = s_nf;

    // ---------------- Phase 1b: full records for binned faces only ----------
    if (tid < nf) {
        int f = s_list[tid];
        int v0, v1, v2;
        face_verts(f, v0, v1, v2);
        float ax = s_vx[v0], ay = s_vy[v0], z0 = s_vz[v0];
        float bx = s_vx[v1], by = s_vy[v1], z1 = s_vz[v1];
        float cx = s_vx[v2], cy = s_vy[v2], z2 = s_vz[v2];
        float* F = &s_f[tid * 28];
        F[0] = ax; F[1] = ay; F[2] = bx; F[3] = by; F[4] = cx; F[5] = cy;
        float dabx = bx - ax, daby = by - ay;
        F[6] = dabx; F[7] = daby;
        F[8] = 1.0f / fmaxf(dabx * dabx + daby * daby, 1e-12f);
        float dbcx = cx - bx, dbcy = cy - by;
        F[9] = dbcx; F[10] = dbcy;
        F[11] = 1.0f / fmaxf(dbcx * dbcx + dbcy * dbcy, 1e-12f);
        float dcax = ax - cx, dcay = ay - cy;
        F[12] = dcax; F[13] = dcay;
        F[14] = 1.0f / fmaxf(dcax * dcax + dcay * dcay, 1e-12f);
        float area = dabx * (cy - ay) - daby * (cx - ax);
        float areas = (fabsf(area) < 1e-8f) ? 1e-8f : area;
        F[15] = 1.0f / areas;
        F[16] = z0; F[17] = z1; F[18] = z2;
        F[19] = z1 * z2; F[20] = z0 * z2; F[21] = z0 * z1;
        int ix0 = v0 % 17, iy0 = v0 / 17;
        int ix1 = v1 % 17, iy1 = v1 / 17;
        int ix2 = v2 % 17, iy2 = v2 / 17;
        F[22] = 1.0f - 0.0625f * (float)ix0; F[23] = 0.0625f * (float)iy0;
        F[24] = 1.0f - 0.0625f * (float)ix1; F[25] = 0.0625f * (float)iy1;
        F[26] = 1.0f - 0.0625f * (float)ix2; F[27] = 0.0625f * (float)iy2;
    }
    __syncthreads();

    // ---------------- Phase 3: 4-way split per-pixel top-8 ----------------
    const int p = tid & 63;       // pixel within tile
    const int sl = tid >> 6;      // slice
    const int x = tileX * 8 + (p & 7);
    const int y = tileY * 8 + (p >> 3);
    const float px = 1.0f - ((float)x + 0.5f) * (1.0f / 64.0f);
    const float py = 1.0f - ((float)y + 0.5f) * (1.0f / 64.0f);

    float kk[8], dd[8];
    int ii[8];
#pragma unroll
    for (int j = 0; j < 8; ++j) { kk[j] = __builtin_inff(); dd[j] = 0.0f; ii[j] = -1; }

    for (int i = sl; i < nf; i += 4) {
        const float4* Fp = (const float4*)(&s_f[i * 28]);
        const float4 f0 = Fp[0], f1 = Fp[1], f2 = Fp[2], f3 = Fp[3];
        const float ax = f0.x, ay = f0.y, bx = f0.z, by = f0.w, cx = f1.x, cy = f1.y;
        float t, ex, ey, d2;
        t = ((px - ax) * f1.z + (py - ay) * f1.w) * f2.x;
        t = fminf(fmaxf(t, 0.0f), 1.0f);
        ex = px - (ax + t * f1.z); ey = py - (ay + t * f1.w);
        d2 = ex * ex + ey * ey;
        t = ((px - bx) * f2.y + (py - by) * f2.z) * f2.w;
        t = fminf(fmaxf(t, 0.0f), 1.0f);
        ex = px - (bx + t * f2.y); ey = py - (by + t * f2.z);
        d2 = fminf(d2, ex * ex + ey * ey);
        t = ((px - cx) * f3.x + (py - cy) * f3.y) * f3.z;
        t = fminf(fmaxf(t, 0.0f), 1.0f);
        ex = px - (cx + t * f3.x); ey = py - (cy + t * f3.y);
        d2 = fminf(d2, ex * ex + ey * ey);
        float w0 = (bx - px) * (cy - py) - (by - py) * (cx - px);
        float w1 = (cx - px) * (ay - py) - (cy - py) * (ax - px);
        float w2 = (ax - px) * (by - py) - (ay - py) * (bx - px);
        float b0 = w0 * f3.w, b1 = w1 * f3.w, b2 = w2 * f3.w;
        bool inside = (b0 >= 0.0f) && (b1 >= 0.0f) && (b2 >= 0.0f);
        float sd = inside ? -d2 : d2;
        if (sd < 1e-4f) {
            const float4 f4 = Fp[4], f5 = Fp[5];
            float n0 = b0 * f4.w, n1 = b1 * f5.x, n2 = b2 * f5.y;
            float den = n0 + n1 + n2;
            den = (fabsf(den) < 1e-10f) ? 1e-10f : den;
            float iden = 1.0f / den;
            float c0 = fmaxf(n0 * iden, 0.0f);
            float c1 = fmaxf(n1 * iden, 0.0f);
            float c2 = fmaxf(n2 * iden, 0.0f);
            float iscn = 1.0f / fmaxf(c0 + c1 + c2, 1e-10f);
            float zp = (c0 * f4.x + c1 * f4.y + c2 * f4.z) * iscn;
            if (zp > 1e-4f && zp < kk[7]) {
#pragma unroll
                for (int j = 7; j >= 1; --j) {
                    bool m1 = zp < kk[j];
                    bool m2 = zp < kk[j - 1];
                    kk[j] = m1 ? (m2 ? kk[j - 1] : zp) : kk[j];
                    dd[j] = m1 ? (m2 ? dd[j - 1] : sd) : dd[j];
                    ii[j] = m1 ? (m2 ? ii[j - 1] : i) : ii[j];
                }
                if (zp < kk[0]) { kk[0] = zp; dd[0] = sd; ii[0] = i; }
            }
        }
    }

#pragma unroll
    for (int j = 0; j < 8; ++j) {
        s_tz[sl][p][j] = kk[j];
        s_td[sl][p][j] = dd[j];
        s_ti[sl][p][j] = ii[j];
    }
    __syncthreads();

    // ---------------- Phase 4a: merge-select (wave 0) ----------------
    // Emits per-pixel selection codes (slice<<3 | idx) for the global top-8
    // and the softmax max (zinv of the nearest valid face). Order within the
    // selected set does not matter for the final sums (commutative), so the
    // heavy per-face work is deferred to all 256 threads in Phase 4b.
    if (tid < 64) {
        int h0 = 0, h1 = 0, h2 = 0, h3 = 0;
        float z0h = s_tz[0][tid][0], z1h = s_tz[1][tid][0];
        float z2h = s_tz[2][tid][0], z3h = s_tz[3][tid][0];
#pragma unroll
        for (int j = 0; j < 8; ++j) {
            int s01 = (z1h < z0h) ? 1 : 0;
            float za = fminf(z0h, z1h);
            int s23 = (z3h < z2h) ? 3 : 2;
            float zb = fminf(z2h, z3h);
            int sw = (zb < za) ? s23 : s01;
            float zw = fminf(za, zb);
            if (j == 0) s_zmax[tid] = fmaxf(1e-10f, (100.0f - zw) * (1.0f / 99.0f));
            int code;
            if (sw == 0)      { code = h0;      ++h0; z0h = (h0 < 8) ? s_tz[0][tid][h0] : __builtin_inff(); }
            else if (sw == 1) { code = 8  | h1; ++h1; z1h = (h1 < 8) ? s_tz[1][tid][h1] : __builtin_inff(); }
            else if (sw == 2) { code = 16 | h2; ++h2; z2h = (h2 < 8) ? s_tz[2][tid][h2] : __builtin_inff(); }
            else              { code = 24 | h3; ++h3; z3h = (h3 < 8) ? s_tz[3][tid][h3] : __builtin_inff(); }
            s_sel[tid][j] = (zw < 3.0e38f) ? code : -1;   // -1: slot empty/inf
        }
    }
    __syncthreads();

    // ---------------- Phase 4b: parallel shade (all 256 threads) ----------
    // Thread handles pixel p, merged slots {2*sl, 2*sl+1}. Weights are
    // independent given zmax (two-pass softmax, as in the reference).
    float pS = 0.0f, pR = 0.0f, pG = 0.0f, pB = 0.0f, pD = 0.0f, pO = 1.0f;
    const float zmx = s_zmax[p];
#pragma unroll
    for (int q = 0; q < 2; ++q) {
        const int code = s_sel[p][2 * sl + q];
        if (code >= 0) {
            const int ss = code >> 3, hh = code & 7;
            const int ci = s_ti[ss][p][hh];
            if (ci >= 0) {
                const float zk = s_tz[ss][p][hh];
                const float sd = s_td[ss][p][hh];
                const float4* Fp = (const float4*)(&s_f[ci * 28]);
                const float4 f0 = Fp[0], f1 = Fp[1], f3 = Fp[3], f4 = Fp[4], f5 = Fp[5], f6 = Fp[6];
                const float ax = f0.x, ay = f0.y, bx = f0.z, by = f0.w, cx = f1.x, cy = f1.y;
                float w0 = (bx - px) * (cy - py) - (by - py) * (cx - px);
                float w1 = (cx - px) * (ay - py) - (cy - py) * (ax - px);
                float w2 = (ax - px) * (by - py) - (ay - py) * (bx - px);
                float b0 = w0 * f3.w, b1 = w1 * f3.w, b2 = w2 * f3.w;
                float n0 = b0 * f4.w, n1 = b1 * f5.x, n2 = b2 * f5.y;
                float den = n0 + n1 + n2;
                den = (fabsf(den) < 1e-10f) ? 1e-10f : den;
                float iden = 1.0f / den;
                float c0 = fmaxf(n0 * iden, 0.0f);
                float c1 = fmaxf(n1 * iden, 0.0f);
                float c2 = fmaxf(n2 * iden, 0.0f);
                float iscn = 1.0f / fmaxf(c0 + c1 + c2, 1e-10f);
                float bc0 = c0 * iscn, bc1 = c1 * iscn, bc2 = c2 * iscn;
                float u = bc0 * f5.z + bc1 * f6.x + bc2 * f6.z;
                float v = bc0 * f5.w + bc1 * f6.y + bc2 * f6.w;
                float tx = u * 127.0f;
                float ty = (1.0f - v) * 127.0f;
                float x0f = fminf(fmaxf(floorf(tx), 0.0f), 127.0f);
                float y0f = fminf(fmaxf(floorf(ty), 0.0f), 127.0f);
                int x0 = (int)x0f, y0 = (int)y0f;
                int x1 = (x0 + 1 < 127) ? x0 + 1 : 127;
                int y1 = (y0 + 1 < 127) ? y0 + 1 : 127;
                float wx = tx - x0f, wy = ty - y0f;
                const float* t00 = texd + (y0 * 128 + x0) * 3;
                const float* t01 = texd + (y0 * 128 + x1) * 3;
                const float* t10 = texd + (y1 * 128 + x0) * 3;
                const float* t11 = texd + (y1 * 128 + x1) * 3;
                float r  = (1.0f - wy) * ((1.0f - wx) * t00[0] + wx * t01[0]) + wy * ((1.0f - wx) * t10[0] + wx * t11[0]);
                float gc = (1.0f - wy) * ((1.0f - wx) * t00[1] + wx * t01[1]) + wy * ((1.0f - wx) * t10[1] + wx * t11[1]);
                float bc = (1.0f - wy) * ((1.0f - wx) * t00[2] + wx * t01[2]) + wy * ((1.0f - wx) * t10[2] + wx * t11[2]);
                float prob = 1.0f / (1.0f + __expf(sd * 1e4f));  // sigmoid(-sd/SIGMA)
                float zi = (100.0f - zk) * (1.0f / 99.0f);
                float wgt = prob * __expf((zi - zmx) * 1e4f);
                pS += wgt; pR += wgt * r; pG += wgt * gc; pB += wgt * bc; pD += wgt * zk;
                pO *= (1.0f - prob);
            }
        }
    }
    s_pS[sl][p] = pS; s_pR[sl][p] = pR; s_pG[sl][p] = pG;
    s_pB[sl][p] = pB; s_pD[sl][p] = pD; s_pO[sl][p] = pO;
    __syncthreads();

    // ---------------- Phase 4c: 4-way reduce + store (wave 0) -------------
    if (tid < 64) {
        float S  = s_pS[0][tid] + s_pS[1][tid] + s_pS[2][tid] + s_pS[3][tid];
        float aR = s_pR[0][tid] + s_pR[1][tid] + s_pR[2][tid] + s_pR[3][tid];
        float aG = s_pG[0][tid] + s_pG[1][tid] + s_pG[2][tid] + s_pG[3][tid];
        float aB = s_pB[0][tid] + s_pB[1][tid] + s_pB[2][tid] + s_pB[3][tid];
        float aD = s_pD[0][tid] + s_pD[1][tid] + s_pD[2][tid] + s_pD[3][tid];
        float om = s_pO[0][tid] * s_pO[1][tid] * s_pO[2][tid] * s_pO[3][tid];
        float delta = __expf((1e-10f - s_zmax[tid]) * 1e4f);
        S += delta;
        aD += delta * 100.0f;  // Z_BACKGROUND
        float invS = 1.0f / S;
        const int o = (y * 128 + x) * 5;
        out[o + 0] = aR * invS;
        out[o + 1] = aG * invS;
        out[o + 2] = aB * invS;
        out[o + 3] = 1.0f - om;
        out[o + 4] = aD * invS;
    }
}

extern "C" void kernel_launch(void* const* d_in, const int* in_sizes, int n_in,
                              void* d_out, int out_size, void* d_ws, size_t ws_size,
                              hipStream_t stream) {
    const float* xy_off = (const float*)d_in[0];
    const float* zg     = (const float*)d_in[1];
    const float* rgb    = (const float*)d_in[2];
    const float* R_in   = (const float*)d_in[3];
    const float* T_in   = (const float*)d_in[4];
    const float* R_out  = (const float*)d_in[5];
    const float* T_out  = (const float*)d_in[6];
    float* out = (float*)d_out;
    nvp_kernel<<<dim3(256), dim3(256), 0, stream>>>(xy_off, zg, rgb, R_in, T_in,
                                                    R_out, T_out, out);
}

// Round 2
// 72.027 us; speedup vs baseline: 1.0317x; 1.0317x over previous
//
#include <hip/hip_runtime.h>
#include <math.h>

#define NVERT 289
#define NFACE 512
#define MAXB 128   // max binned faces per 8x8 tile (analysis: ~10-16 typical)

__device__ __forceinline__ float frcp(float x) {
#if __has_builtin(__builtin_amdgcn_rcpf)
    return __builtin_amdgcn_rcpf(x);   // v_rcp_f32, ~1ulp — tolerance is 3.9e-3
#else
    return 1.0f / x;
#endif
}

// Decode face f -> vertex indices (matches _build_faces ordering).
__device__ __forceinline__ void face_verts(int f, int& v0, int& v1, int& v2) {
    int g = f >> 6, i = f & 63, rr = i >> 3, cc = i & 7;
    int ny = 2 * rr + (g >> 2);
    int oddx = ((g & 2) ? 0 : 1) ^ (g >> 2);
    int nx = 2 * cc + oddx;
    int p = g & 3;
    const int dy0[4] = {0, 0, 0, 1};
    const int dy1[4] = {0, 1, 0, 0};
    const int dx2[4] = {0, 1, 1, 0};
    v0 = (ny + dy0[p]) * 17 + nx + 1;
    v1 = (ny + dy1[p]) * 17 + nx;
    v2 = (ny + 1) * 17 + nx + dx2[p];
}

// 256 blocks: one 8x8-pixel tile per CU. 512 threads: 8 slices x 64 pixels.
// All phases single-pass; compaction via per-wave ballot + LDS prefix (no
// serial wave0 loop); sd recomputed in shade phase (no s_td array).
__global__ __launch_bounds__(512) void nvp_kernel(
    const float* __restrict__ xy_off,
    const float* __restrict__ z_grid,
    const float* __restrict__ texd,
    const float* __restrict__ R_in,
    const float* __restrict__ T_in,
    const float* __restrict__ R_out,
    const float* __restrict__ T_out,
    float* __restrict__ out)
{
    __shared__ __align__(16) float s_f[MAXB * 28];
    __shared__ float s_vx[NVERT], s_vy[NVERT], s_vz[NVERT];
    __shared__ int s_list[MAXB];
    __shared__ int s_nf;
    __shared__ int s_wcnt[8];
    __shared__ float s_tz[8][64][9];          // per-slice top-8 z (pad->9)
    __shared__ unsigned char s_ti[8][64][9];  // per-slice top-8 face rec idx
    __shared__ int   s_sel[64][9];            // merged top-8 selection codes
    __shared__ float s_zmax[64];              // per-pixel softmax max (zinv)
    __shared__ float s_pS[8][64], s_pR[8][64], s_pG[8][64];
    __shared__ float s_pB[8][64], s_pD[8][64], s_pO[8][64];

    const int tid = threadIdx.x;
    const int lane = tid & 63;
    const int wv = tid >> 6;
    const int tileX = blockIdx.x & 15;
    const int tileY = blockIdx.x >> 4;

    const float SC = 0.57735026918962576f;        // tan(30 deg)
    const float SI = 1.0f / 0.57735026918962576f; // 1/SCALE
    const float INF = __builtin_inff();

    // ---------------- Phase 0: screen-space vertices (single pass) --------
    if (tid < NVERT) {
        int v = tid;
        int ix = v % 17, iy = v / 17;
        float gx = -1.0f + 0.125f * (float)ix;
        float gy = -1.0f + 0.125f * (float)iy;
        float2 off = ((const float2*)xy_off)[v];
        float sx = (gx + off.x) * SC;
        float sy = (gy + off.y) * SC;
        float z = z_grid[v];
        float X = sx * z, Y = sy * z, Z = z;
        float p0 = X - T_in[0], p1 = Y - T_in[1], p2 = Z - T_in[2];
        float wxx = R_in[0] * p0 + R_in[1] * p1 + R_in[2] * p2;
        float wyy = R_in[3] * p0 + R_in[4] * p1 + R_in[5] * p2;
        float wzz = R_in[6] * p0 + R_in[7] * p1 + R_in[8] * p2;
        float vx = wxx * R_out[0] + wyy * R_out[3] + wzz * R_out[6] + T_out[0];
        float vy = wxx * R_out[1] + wyy * R_out[4] + wzz * R_out[7] + T_out[1];
        float vz = wxx * R_out[2] + wyy * R_out[5] + wzz * R_out[8] + T_out[2];
        float zden = (vz >= 0.0f) ? fmaxf(vz, 0.01f) : fminf(vz, -0.01f);
        float rz = frcp(zden);
        s_vx[v] = SI * vx * rz;
        s_vy[v] = SI * vy * rz;
        s_vz[v] = vz;
    }
    __syncthreads();

    // tile NDC bounds (px decreasing in x, py decreasing in y); 8px tile
    const float pxmax = 1.0f - ((float)(tileX * 8) + 0.5f) * (1.0f / 64.0f);
    const float pxmin = 1.0f - ((float)(tileX * 8) + 7.5f) * (1.0f / 64.0f);
    const float pymax = 1.0f - ((float)(tileY * 8) + 0.5f) * (1.0f / 64.0f);
    const float pymin = 1.0f - ((float)(tileY * 8) + 7.5f) * (1.0f / 64.0f);
    const float MARG = 0.015f;  // validity needs edge-dist < 0.01 NDC

    // ------- Phase 1a: bbox test + per-wave ballot counts (single pass) ----
    bool ov;
    {
        int f = tid;  // 512 threads == 512 faces
        int v0, v1, v2;
        face_verts(f, v0, v1, v2);
        float ax = s_vx[v0], ay = s_vy[v0];
        float bx = s_vx[v1], by = s_vy[v1];
        float cx = s_vx[v2], cy = s_vy[v2];
        float minx = fminf(ax, fminf(bx, cx)), maxx = fmaxf(ax, fmaxf(bx, cx));
        float miny = fminf(ay, fminf(by, cy)), maxy = fmaxf(ay, fmaxf(by, cy));
        ov = (minx - MARG <= pxmax) && (maxx + MARG >= pxmin) &&
             (miny - MARG <= pymax) && (maxy + MARG >= pymin);
    }
    unsigned long long wmask = __ballot(ov);
    if (lane == 0) s_wcnt[wv] = (int)__popcll(wmask);
    __syncthreads();

    // ------- Phase 2: ordered scatter via cross-wave prefix ----------------
    {
        int base = 0, total = 0;
#pragma unroll
        for (int w = 0; w < 8; ++w) {
            int c = s_wcnt[w];
            if (w < wv) base += c;
            total += c;
        }
        if (ov) {
            int pos = base + (int)__popcll(wmask & ((1ull << lane) - 1ull));
            if (pos < MAXB) s_list[pos] = tid;
        }
        if (tid == 0) s_nf = (total < MAXB) ? total : MAXB;
    }
    __syncthreads();

    const int nf = s_nf;

    // ---------------- Phase 1b: full records for binned faces only ----------
    if (tid < nf) {
        int f = s_list[tid];
        int v0, v1, v2;
        face_verts(f, v0, v1, v2);
        float ax = s_vx[v0], ay = s_vy[v0], z0 = s_vz[v0];
        float bx = s_vx[v1], by = s_vy[v1], z1 = s_vz[v1];
        float cx = s_vx[v2], cy = s_vy[v2], z2 = s_vz[v2];
        float* F = &s_f[tid * 28];
        F[0] = ax; F[1] = ay; F[2] = bx; F[3] = by; F[4] = cx; F[5] = cy;
        float dabx = bx - ax, daby = by - ay;
        F[6] = dabx; F[7] = daby;
        F[8] = frcp(fmaxf(dabx * dabx + daby * daby, 1e-12f));
        float dbcx = cx - bx, dbcy = cy - by;
        F[9] = dbcx; F[10] = dbcy;
        F[11] = frcp(fmaxf(dbcx * dbcx + dbcy * dbcy, 1e-12f));
        float dcax = ax - cx, dcay = ay - cy;
        F[12] = dcax; F[13] = dcay;
        F[14] = frcp(fmaxf(dcax * dcax + dcay * dcay, 1e-12f));
        float area = dabx * (cy - ay) - daby * (cx - ax);
        float areas = (fabsf(area) < 1e-8f) ? 1e-8f : area;
        F[15] = frcp(areas);
        F[16] = z0; F[17] = z1; F[18] = z2;
        F[19] = z1 * z2; F[20] = z0 * z2; F[21] = z0 * z1;
        int ix0 = v0 % 17, iy0 = v0 / 17;
        int ix1 = v1 % 17, iy1 = v1 / 17;
        int ix2 = v2 % 17, iy2 = v2 / 17;
        F[22] = 1.0f - 0.0625f * (float)ix0; F[23] = 0.0625f * (float)iy0;
        F[24] = 1.0f - 0.0625f * (float)ix1; F[25] = 0.0625f * (float)iy1;
        F[26] = 1.0f - 0.0625f * (float)ix2; F[27] = 0.0625f * (float)iy2;
    }
    __syncthreads();

    // ---------------- Phase 3: 8-way split per-pixel top-8 ----------------
    const int p = lane;           // pixel within tile
    const int sl = wv;            // slice
    const int x = tileX * 8 + (p & 7);
    const int y = tileY * 8 + (p >> 3);
    const float px = 1.0f - ((float)x + 0.5f) * (1.0f / 64.0f);
    const float py = 1.0f - ((float)y + 0.5f) * (1.0f / 64.0f);

    float kk[8];
    int ii[8];
#pragma unroll
    for (int j = 0; j < 8; ++j) { kk[j] = INF; ii[j] = 255; }

    for (int i = sl; i < nf; i += 8) {
        const float4* Fp = (const float4*)(&s_f[i * 28]);
        const float4 f0 = Fp[0], f1 = Fp[1], f2 = Fp[2], f3 = Fp[3];
        const float ax = f0.x, ay = f0.y, bx = f0.z, by = f0.w, cx = f1.x, cy = f1.y;
        float t, ex, ey, d2;
        t = ((px - ax) * f1.z + (py - ay) * f1.w) * f2.x;
        t = fminf(fmaxf(t, 0.0f), 1.0f);
        ex = px - (ax + t * f1.z); ey = py - (ay + t * f1.w);
        d2 = ex * ex + ey * ey;
        t = ((px - bx) * f2.y + (py - by) * f2.z) * f2.w;
        t = fminf(fmaxf(t, 0.0f), 1.0f);
        ex = px - (bx + t * f2.y); ey = py - (by + t * f2.z);
        d2 = fminf(d2, ex * ex + ey * ey);
        t = ((px - cx) * f3.x + (py - cy) * f3.y) * f3.z;
        t = fminf(fmaxf(t, 0.0f), 1.0f);
        ex = px - (cx + t * f3.x); ey = py - (cy + t * f3.y);
        d2 = fminf(d2, ex * ex + ey * ey);
        float w0 = (bx - px) * (cy - py) - (by - py) * (cx - px);
        float w1 = (cx - px) * (ay - py) - (cy - py) * (ax - px);
        float w2 = (ax - px) * (by - py) - (ay - py) * (bx - px);
        float b0 = w0 * f3.w, b1 = w1 * f3.w, b2 = w2 * f3.w;
        bool inside = (b0 >= 0.0f) && (b1 >= 0.0f) && (b2 >= 0.0f);
        float sd = inside ? -d2 : d2;
        if (sd < 1e-4f) {
            const float4 f4 = Fp[4], f5 = Fp[5];
            float n0 = b0 * f4.w, n1 = b1 * f5.x, n2 = b2 * f5.y;
            float den = n0 + n1 + n2;
            den = (fabsf(den) < 1e-10f) ? 1e-10f : den;
            float iden = frcp(den);
            float c0 = fmaxf(n0 * iden, 0.0f);
            float c1 = fmaxf(n1 * iden, 0.0f);
            float c2 = fmaxf(n2 * iden, 0.0f);
            float iscn = frcp(fmaxf(c0 + c1 + c2, 1e-10f));
            float zp = (c0 * f4.x + c1 * f4.y + c2 * f4.z) * iscn;
            if (zp > 1e-4f && zp < kk[7]) {
#pragma unroll
                for (int j = 7; j >= 1; --j) {
                    bool m1 = zp < kk[j];
                    bool m2 = zp < kk[j - 1];
                    kk[j] = m1 ? (m2 ? kk[j - 1] : zp) : kk[j];
                    ii[j] = m1 ? (m2 ? ii[j - 1] : i) : ii[j];
                }
                if (zp < kk[0]) { kk[0] = zp; ii[0] = i; }
            }
        }
    }

#pragma unroll
    for (int j = 0; j < 8; ++j) {
        s_tz[sl][p][j] = kk[j];
        s_ti[sl][p][j] = (unsigned char)ii[j];
    }
    __syncthreads();

    // ---------------- Phase 4a: 8-way merge-select (wave 0) ----------------
    if (tid < 64) {
        const int pp = tid;
        float z0 = s_tz[0][pp][0], z1 = s_tz[1][pp][0];
        float z2 = s_tz[2][pp][0], z3 = s_tz[3][pp][0];
        float z4 = s_tz[4][pp][0], z5 = s_tz[5][pp][0];
        float z6 = s_tz[6][pp][0], z7 = s_tz[7][pp][0];
        int h0 = 0, h1 = 0, h2 = 0, h3 = 0, h4 = 0, h5 = 0, h6 = 0, h7 = 0;
#pragma unroll
        for (int j = 0; j < 8; ++j) {
            int sA = (z1 < z0) ? 1 : 0; float zA = fminf(z0, z1);
            int sB = (z3 < z2) ? 3 : 2; float zB = fminf(z2, z3);
            int sC = (z5 < z4) ? 5 : 4; float zC = fminf(z4, z5);
            int sD = (z7 < z6) ? 7 : 6; float zD = fminf(z6, z7);
            int sAB = (zB < zA) ? sB : sA; float zAB = fminf(zA, zB);
            int sCD = (zD < zC) ? sD : sC; float zCD = fminf(zC, zD);
            int sw = (zCD < zAB) ? sCD : sAB; float zw = fminf(zAB, zCD);
            if (j == 0) s_zmax[pp] = fmaxf(1e-10f, (100.0f - zw) * (1.0f / 99.0f));
            int code = -1;
            if (zw < 3.0e38f) {
                if      (sw == 0) { code =      h0; ++h0; z0 = (h0 < 8) ? s_tz[0][pp][h0] : INF; }
                else if (sw == 1) { code = 8  | h1; ++h1; z1 = (h1 < 8) ? s_tz[1][pp][h1] : INF; }
                else if (sw == 2) { code = 16 | h2; ++h2; z2 = (h2 < 8) ? s_tz[2][pp][h2] : INF; }
                else if (sw == 3) { code = 24 | h3; ++h3; z3 = (h3 < 8) ? s_tz[3][pp][h3] : INF; }
                else if (sw == 4) { code = 32 | h4; ++h4; z4 = (h4 < 8) ? s_tz[4][pp][h4] : INF; }
                else if (sw == 5) { code = 40 | h5; ++h5; z5 = (h5 < 8) ? s_tz[5][pp][h5] : INF; }
                else if (sw == 6) { code = 48 | h6; ++h6; z6 = (h6 < 8) ? s_tz[6][pp][h6] : INF; }
                else              { code = 56 | h7; ++h7; z7 = (h7 < 8) ? s_tz[7][pp][h7] : INF; }
            }
            s_sel[pp][j] = code;
        }
    }
    __syncthreads();

    // ---------------- Phase 4b: parallel shade (all 512 threads) ----------
    // Thread handles pixel p, merged slot sl. Weights independent given zmax
    // (two-pass softmax, as in the reference). sd recomputed from the record.
    float pS = 0.0f, pR = 0.0f, pG = 0.0f, pB = 0.0f, pD = 0.0f, pO = 1.0f;
    {
        const int code = s_sel[p][sl];
        if (code >= 0) {
            const int ss = code >> 3, hh = code & 7;
            const int ci = (int)s_ti[ss][p][hh];
            const float zk = s_tz[ss][p][hh];
            const float zmx = s_zmax[p];
            const float4* Fp = (const float4*)(&s_f[ci * 28]);
            const float4 f0 = Fp[0], f1 = Fp[1], f2 = Fp[2], f3 = Fp[3];
            const float4 f4 = Fp[4], f5 = Fp[5], f6 = Fp[6];
            const float ax = f0.x, ay = f0.y, bx = f0.z, by = f0.w, cx = f1.x, cy = f1.y;
            // recompute signed distance (same formulas as Phase 3)
            float t, ex, ey, d2;
            t = ((px - ax) * f1.z + (py - ay) * f1.w) * f2.x;
            t = fminf(fmaxf(t, 0.0f), 1.0f);
            ex = px - (ax + t * f1.z); ey = py - (ay + t * f1.w);
            d2 = ex * ex + ey * ey;
            t = ((px - bx) * f2.y + (py - by) * f2.z) * f2.w;
            t = fminf(fmaxf(t, 0.0f), 1.0f);
            ex = px - (bx + t * f2.y); ey = py - (by + t * f2.z);
            d2 = fminf(d2, ex * ex + ey * ey);
            t = ((px - cx) * f3.x + (py - cy) * f3.y) * f3.z;
            t = fminf(fmaxf(t, 0.0f), 1.0f);
            ex = px - (cx + t * f3.x); ey = py - (cy + t * f3.y);
            d2 = fminf(d2, ex * ex + ey * ey);
            float w0 = (bx - px) * (cy - py) - (by - py) * (cx - px);
            float w1 = (cx - px) * (ay - py) - (cy - py) * (ax - px);
            float w2 = (ax - px) * (by - py) - (ay - py) * (bx - px);
            float b0 = w0 * f3.w, b1 = w1 * f3.w, b2 = w2 * f3.w;
            bool inside = (b0 >= 0.0f) && (b1 >= 0.0f) && (b2 >= 0.0f);
            float sd = inside ? -d2 : d2;
            float n0 = b0 * f4.w, n1 = b1 * f5.x, n2 = b2 * f5.y;
            float den = n0 + n1 + n2;
            den = (fabsf(den) < 1e-10f) ? 1e-10f : den;
            float iden = frcp(den);
            float c0 = fmaxf(n0 * iden, 0.0f);
            float c1 = fmaxf(n1 * iden, 0.0f);
            float c2 = fmaxf(n2 * iden, 0.0f);
            float iscn = frcp(fmaxf(c0 + c1 + c2, 1e-10f));
            float bc0 = c0 * iscn, bc1 = c1 * iscn, bc2 = c2 * iscn;
            float u = bc0 * f5.z + bc1 * f6.x + bc2 * f6.z;
            float v = bc0 * f5.w + bc1 * f6.y + bc2 * f6.w;
            float tx = u * 127.0f;
            float ty = (1.0f - v) * 127.0f;
            float x0f = fminf(fmaxf(floorf(tx), 0.0f), 127.0f);
            float y0f = fminf(fmaxf(floorf(ty), 0.0f), 127.0f);
            int x0 = (int)x0f, y0 = (int)y0f;
            int x1 = (x0 + 1 < 127) ? x0 + 1 : 127;
            int y1 = (y0 + 1 < 127) ? y0 + 1 : 127;
            float wx = tx - x0f, wy = ty - y0f;
            const float* t00 = texd + (y0 * 128 + x0) * 3;
            const float* t01 = texd + (y0 * 128 + x1) * 3;
            const float* t10 = texd + (y1 * 128 + x0) * 3;
            const float* t11 = texd + (y1 * 128 + x1) * 3;
            float r  = (1.0f - wy) * ((1.0f - wx) * t00[0] + wx * t01[0]) + wy * ((1.0f - wx) * t10[0] + wx * t11[0]);
            float gc = (1.0f - wy) * ((1.0f - wx) * t00[1] + wx * t01[1]) + wy * ((1.0f - wx) * t10[1] + wx * t11[1]);
            float bc = (1.0f - wy) * ((1.0f - wx) * t00[2] + wx * t01[2]) + wy * ((1.0f - wx) * t10[2] + wx * t11[2]);
            float prob = frcp(1.0f + __expf(sd * 1e4f));  // sigmoid(-sd/SIGMA)
            float zi = (100.0f - zk) * (1.0f / 99.0f);
            float wgt = prob * __expf((zi - zmx) * 1e4f);
            pS = wgt; pR = wgt * r; pG = wgt * gc; pB = wgt * bc; pD = wgt * zk;
            pO = 1.0f - prob;
        }
    }
    s_pS[sl][p] = pS; s_pR[sl][p] = pR; s_pG[sl][p] = pG;
    s_pB[sl][p] = pB; s_pD[sl][p] = pD; s_pO[sl][p] = pO;
    __syncthreads();

    // ---------------- Phase 4c: 8-way reduce + store (wave 0) -------------
    if (tid < 64) {
        float S = 0.0f, aR = 0.0f, aG = 0.0f, aB = 0.0f, aD = 0.0f, om = 1.0f;
#pragma unroll
        for (int w = 0; w < 8; ++w) {
            S  += s_pS[w][tid];
            aR += s_pR[w][tid];
            aG += s_pG[w][tid];
            aB += s_pB[w][tid];
            aD += s_pD[w][tid];
            om *= s_pO[w][tid];
        }
        float delta = __expf((1e-10f - s_zmax[tid]) * 1e4f);
        S += delta;
        aD += delta * 100.0f;  // Z_BACKGROUND
        float invS = frcp(S);
        const int o = (y * 128 + x) * 5;
        out[o + 0] = aR * invS;
        out[o + 1] = aG * invS;
        out[o + 2] = aB * invS;
        out[o + 3] = 1.0f - om;
        out[o + 4] = aD * invS;
    }
}

extern "C" void kernel_launch(void* const* d_in, const int* in_sizes, int n_in,
                              void* d_out, int out_size, void* d_ws, size_t ws_size,
                              hipStream_t stream) {
    const float* xy_off = (const float*)d_in[0];
    const float* zg     = (const float*)d_in[1];
    const float* rgb    = (const float*)d_in[2];
    const float* R_in   = (const float*)d_in[3];
    const float* T_in   = (const float*)d_in[4];
    const float* R_out  = (const float*)d_in[5];
    const float* T_out  = (const float*)d_in[6];
    float* out = (float*)d_out;
    nvp_kernel<<<dim3(256), dim3(512), 0, stream>>>(xy_off, zg, rgb, R_in, T_in,
                                                    R_out, T_out, out);
}

// Round 3
// 71.835 us; speedup vs baseline: 1.0345x; 1.0027x over previous
//
#include <hip/hip_runtime.h>
#include <math.h>

#define NVERT 289
#define NFACE 512
#define MAXB 128   // max binned faces per 8x8 tile (analysis: ~10-16 typical)

__device__ __forceinline__ float frcp(float x) {
#if __has_builtin(__builtin_amdgcn_rcpf)
    return __builtin_amdgcn_rcpf(x);   // v_rcp_f32, ~1ulp — tolerance is 3.9e-3
#else
    return 1.0f / x;
#endif
}

// Decode face f -> vertex indices (matches _build_faces ordering).
__device__ __forceinline__ void face_verts(int f, int& v0, int& v1, int& v2) {
    int g = f >> 6, i = f & 63, rr = i >> 3, cc = i & 7;
    int ny = 2 * rr + (g >> 2);
    int oddx = ((g & 2) ? 0 : 1) ^ (g >> 2);
    int nx = 2 * cc + oddx;
    int p = g & 3;
    const int dy0[4] = {0, 0, 0, 1};
    const int dy1[4] = {0, 1, 0, 0};
    const int dx2[4] = {0, 1, 1, 0};
    v0 = (ny + dy0[p]) * 17 + nx + 1;
    v1 = (ny + dy1[p]) * 17 + nx;
    v2 = (ny + 1) * 17 + nx + dx2[p];
}

// 256 blocks: one 8x8-pixel tile per CU. 512 threads = 64 groups of 8 lanes;
// each group owns ONE pixel. After face binning (3 barriers total), the
// entire top-8 select / merge / shade / reduce path is intra-group shuffles:
// no further __syncthreads, no LDS staging of per-pixel state.
__global__ __launch_bounds__(512) void nvp_kernel(
    const float* __restrict__ xy_off,
    const float* __restrict__ z_grid,
    const float* __restrict__ texd,
    const float* __restrict__ R_in,
    const float* __restrict__ T_in,
    const float* __restrict__ R_out,
    const float* __restrict__ T_out,
    float* __restrict__ out)
{
    __shared__ __align__(16) float s_f[MAXB * 28];
    __shared__ float s_vx[NVERT], s_vy[NVERT], s_vz[NVERT];
    __shared__ int s_wcnt[8];
    __shared__ int s_nf;

    const int tid = threadIdx.x;
    const int lane = tid & 63;
    const int wv = tid >> 6;
    const int tileX = blockIdx.x & 15;
    const int tileY = blockIdx.x >> 4;

    const float SC = 0.57735026918962576f;        // tan(30 deg)
    const float SI = 1.0f / 0.57735026918962576f; // 1/SCALE
    const float INF = __builtin_inff();

    // ---------------- Phase 0: screen-space vertices (single pass) --------
    if (tid < NVERT) {
        int v = tid;
        int ix = v % 17, iy = v / 17;
        float gx = -1.0f + 0.125f * (float)ix;
        float gy = -1.0f + 0.125f * (float)iy;
        float2 off = ((const float2*)xy_off)[v];
        float sx = (gx + off.x) * SC;
        float sy = (gy + off.y) * SC;
        float z = z_grid[v];
        float X = sx * z, Y = sy * z, Z = z;
        float p0 = X - T_in[0], p1 = Y - T_in[1], p2 = Z - T_in[2];
        float wxx = R_in[0] * p0 + R_in[1] * p1 + R_in[2] * p2;
        float wyy = R_in[3] * p0 + R_in[4] * p1 + R_in[5] * p2;
        float wzz = R_in[6] * p0 + R_in[7] * p1 + R_in[8] * p2;
        float vx = wxx * R_out[0] + wyy * R_out[3] + wzz * R_out[6] + T_out[0];
        float vy = wxx * R_out[1] + wyy * R_out[4] + wzz * R_out[7] + T_out[1];
        float vz = wxx * R_out[2] + wyy * R_out[5] + wzz * R_out[8] + T_out[2];
        float zden = (vz >= 0.0f) ? fmaxf(vz, 0.01f) : fminf(vz, -0.01f);
        float rz = frcp(zden);
        s_vx[v] = SI * vx * rz;
        s_vy[v] = SI * vy * rz;
        s_vz[v] = vz;
    }
    __syncthreads();

    // tile NDC bounds (px decreasing in x, py decreasing in y); 8px tile
    const float pxmax = 1.0f - ((float)(tileX * 8) + 0.5f) * (1.0f / 64.0f);
    const float pxmin = 1.0f - ((float)(tileX * 8) + 7.5f) * (1.0f / 64.0f);
    const float pymax = 1.0f - ((float)(tileY * 8) + 0.5f) * (1.0f / 64.0f);
    const float pymin = 1.0f - ((float)(tileY * 8) + 7.5f) * (1.0f / 64.0f);
    const float MARG = 0.015f;  // validity needs edge-dist < 0.01 NDC

    // ------- Phase 1a: bbox test + per-wave ballot counts (single pass) ----
    bool ov;
    {
        int f = tid;  // 512 threads == 512 faces
        int v0, v1, v2;
        face_verts(f, v0, v1, v2);
        float ax = s_vx[v0], ay = s_vy[v0];
        float bx = s_vx[v1], by = s_vy[v1];
        float cx = s_vx[v2], cy = s_vy[v2];
        float minx = fminf(ax, fminf(bx, cx)), maxx = fmaxf(ax, fmaxf(bx, cx));
        float miny = fminf(ay, fminf(by, cy)), maxy = fmaxf(ay, fmaxf(by, cy));
        ov = (minx - MARG <= pxmax) && (maxx + MARG >= pxmin) &&
             (miny - MARG <= pymax) && (maxy + MARG >= pymin);
    }
    unsigned long long wmask = __ballot(ov);
    if (lane == 0) s_wcnt[wv] = (int)__popcll(wmask);
    __syncthreads();

    // ------- Phase 2: prefix + build record directly at compacted slot -----
    {
        int base = 0, total = 0;
#pragma unroll
        for (int w = 0; w < 8; ++w) {
            int c = s_wcnt[w];
            if (w < wv) base += c;
            total += c;
        }
        if (tid == 0) s_nf = (total < MAXB) ? total : MAXB;
        if (ov) {
            int pos = base + (int)__popcll(wmask & ((1ull << lane) - 1ull));
            if (pos < MAXB) {
                int f = tid;
                int v0, v1, v2;
                face_verts(f, v0, v1, v2);
                float ax = s_vx[v0], ay = s_vy[v0], z0 = s_vz[v0];
                float bx = s_vx[v1], by = s_vy[v1], z1 = s_vz[v1];
                float cx = s_vx[v2], cy = s_vy[v2], z2 = s_vz[v2];
                float* F = &s_f[pos * 28];
                F[0] = ax; F[1] = ay; F[2] = bx; F[3] = by; F[4] = cx; F[5] = cy;
                float dabx = bx - ax, daby = by - ay;
                F[6] = dabx; F[7] = daby;
                F[8] = frcp(fmaxf(dabx * dabx + daby * daby, 1e-12f));
                float dbcx = cx - bx, dbcy = cy - by;
                F[9] = dbcx; F[10] = dbcy;
                F[11] = frcp(fmaxf(dbcx * dbcx + dbcy * dbcy, 1e-12f));
                float dcax = ax - cx, dcay = ay - cy;
                F[12] = dcax; F[13] = dcay;
                F[14] = frcp(fmaxf(dcax * dcax + dcay * dcay, 1e-12f));
                float area = dabx * (cy - ay) - daby * (cx - ax);
                float areas = (fabsf(area) < 1e-8f) ? 1e-8f : area;
                F[15] = frcp(areas);
                F[16] = z0; F[17] = z1; F[18] = z2;
                F[19] = z1 * z2; F[20] = z0 * z2; F[21] = z0 * z1;
                int ix0 = v0 % 17, iy0 = v0 / 17;
                int ix1 = v1 % 17, iy1 = v1 / 17;
                int ix2 = v2 % 17, iy2 = v2 / 17;
                F[22] = 1.0f - 0.0625f * (float)ix0; F[23] = 0.0625f * (float)iy0;
                F[24] = 1.0f - 0.0625f * (float)ix1; F[25] = 0.0625f * (float)iy1;
                F[26] = 1.0f - 0.0625f * (float)ix2; F[27] = 0.0625f * (float)iy2;
            }
        }
    }
    __syncthreads();

    const int nf = s_nf;

    // ---------------- Phase 3: per-group (8 lanes / pixel) top-8 -----------
    const int l = tid & 7;        // lane within group
    const int p = tid >> 3;       // pixel within tile (group id)
    const int x = tileX * 8 + (p & 7);
    const int y = tileY * 8 + (p >> 3);
    const float px = 1.0f - ((float)x + 0.5f) * (1.0f / 64.0f);
    const float py = 1.0f - ((float)y + 0.5f) * (1.0f / 64.0f);

    float kk[8];
    int ii[8];
#pragma unroll
    for (int j = 0; j < 8; ++j) { kk[j] = INF; ii[j] = -1; }

    for (int i = l; i < nf; i += 8) {
        const float4* Fp = (const float4*)(&s_f[i * 28]);
        const float4 f0 = Fp[0], f1 = Fp[1], f2 = Fp[2], f3 = Fp[3];
        const float ax = f0.x, ay = f0.y, bx = f0.z, by = f0.w, cx = f1.x, cy = f1.y;
        float t, ex, ey, d2;
        t = ((px - ax) * f1.z + (py - ay) * f1.w) * f2.x;
        t = fminf(fmaxf(t, 0.0f), 1.0f);
        ex = px - (ax + t * f1.z); ey = py - (ay + t * f1.w);
        d2 = ex * ex + ey * ey;
        t = ((px - bx) * f2.y + (py - by) * f2.z) * f2.w;
        t = fminf(fmaxf(t, 0.0f), 1.0f);
        ex = px - (bx + t * f2.y); ey = py - (by + t * f2.z);
        d2 = fminf(d2, ex * ex + ey * ey);
        t = ((px - cx) * f3.x + (py - cy) * f3.y) * f3.z;
        t = fminf(fmaxf(t, 0.0f), 1.0f);
        ex = px - (cx + t * f3.x); ey = py - (cy + t * f3.y);
        d2 = fminf(d2, ex * ex + ey * ey);
        float w0 = (bx - px) * (cy - py) - (by - py) * (cx - px);
        float w1 = (cx - px) * (ay - py) - (cy - py) * (ax - px);
        float w2 = (ax - px) * (by - py) - (ay - py) * (bx - px);
        float b0 = w0 * f3.w, b1 = w1 * f3.w, b2 = w2 * f3.w;
        bool inside = (b0 >= 0.0f) && (b1 >= 0.0f) && (b2 >= 0.0f);
        float sd = inside ? -d2 : d2;
        if (sd < 1e-4f) {
            const float4 f4 = Fp[4], f5 = Fp[5];
            float n0 = b0 * f4.w, n1 = b1 * f5.x, n2 = b2 * f5.y;
            float den = n0 + n1 + n2;
            den = (fabsf(den) < 1e-10f) ? 1e-10f : den;
            float iden = frcp(den);
            float c0 = fmaxf(n0 * iden, 0.0f);
            float c1 = fmaxf(n1 * iden, 0.0f);
            float c2 = fmaxf(n2 * iden, 0.0f);
            float iscn = frcp(fmaxf(c0 + c1 + c2, 1e-10f));
            float zp = (c0 * f4.x + c1 * f4.y + c2 * f4.z) * iscn;
            if (zp > 1e-4f && zp < kk[7]) {
#pragma unroll
                for (int j = 7; j >= 1; --j) {
                    bool m1 = zp < kk[j];
                    bool m2 = zp < kk[j - 1];
                    kk[j] = m1 ? (m2 ? kk[j - 1] : zp) : kk[j];
                    ii[j] = m1 ? (m2 ? ii[j - 1] : i) : ii[j];
                }
                if (zp < kk[0]) { kk[0] = zp; ii[0] = i; }
            }
        }
    }

    // ---------------- Phase 4: shuffle-based 8-way merge (no barrier) ------
    // 8 pop-min steps across the group; winner j lands in lane j's registers.
    float hz = kk[0];
    int hf = ii[0];
    float selz = INF;
    int self_ = -1;
    float zfirst = INF;
#pragma unroll
    for (int j = 0; j < 8; ++j) {
        float mz = hz;
        int ml = l;
#pragma unroll
        for (int m = 1; m < 8; m <<= 1) {
            float oz = __shfl_xor(mz, m, 8);
            int ol = __shfl_xor(ml, m, 8);
            bool take = (oz < mz) || ((oz == mz) && (ol < ml));
            mz = take ? oz : mz;
            ml = take ? ol : ml;
        }
        int wf = __shfl(hf, ml, 8);
        if (j == 0) zfirst = mz;
        if (l == j) { selz = mz; self_ = wf; }
        if (ml == l) {   // I'm the winner: pop my sorted list (static shifts)
#pragma unroll
            for (int q = 0; q < 7; ++q) { kk[q] = kk[q + 1]; ii[q] = ii[q + 1]; }
            kk[7] = INF; ii[7] = -1;
            hz = kk[0]; hf = ii[0];
        }
    }
    const float zmx = fmaxf(1e-10f, (100.0f - zfirst) * (1.0f / 99.0f));

    // ---------------- Phase 5: shade (1 face per lane, registers only) -----
    float pS = 0.0f, pR = 0.0f, pG = 0.0f, pB = 0.0f, pD = 0.0f, pO = 1.0f;
    if (selz < 3.0e38f) {
        const int ci = self_;
        const float zk = selz;
        const float4* Fp = (const float4*)(&s_f[ci * 28]);
        const float4 f0 = Fp[0], f1 = Fp[1], f2 = Fp[2], f3 = Fp[3];
        const float4 f4 = Fp[4], f5 = Fp[5], f6 = Fp[6];
        const float ax = f0.x, ay = f0.y, bx = f0.z, by = f0.w, cx = f1.x, cy = f1.y;
        // recompute signed distance (same formulas as Phase 3)
        float t, ex, ey, d2;
        t = ((px - ax) * f1.z + (py - ay) * f1.w) * f2.x;
        t = fminf(fmaxf(t, 0.0f), 1.0f);
        ex = px - (ax + t * f1.z); ey = py - (ay + t * f1.w);
        d2 = ex * ex + ey * ey;
        t = ((px - bx) * f2.y + (py - by) * f2.z) * f2.w;
        t = fminf(fmaxf(t, 0.0f), 1.0f);
        ex = px - (bx + t * f2.y); ey = py - (by + t * f2.z);
        d2 = fminf(d2, ex * ex + ey * ey);
        t = ((px - cx) * f3.x + (py - cy) * f3.y) * f3.z;
        t = fminf(fmaxf(t, 0.0f), 1.0f);
        ex = px - (cx + t * f3.x); ey = py - (cy + t * f3.y);
        d2 = fminf(d2, ex * ex + ey * ey);
        float w0 = (bx - px) * (cy - py) - (by - py) * (cx - px);
        float w1 = (cx - px) * (ay - py) - (cy - py) * (ax - px);
        float w2 = (ax - px) * (by - py) - (ay - py) * (bx - px);
        float b0 = w0 * f3.w, b1 = w1 * f3.w, b2 = w2 * f3.w;
        bool inside = (b0 >= 0.0f) && (b1 >= 0.0f) && (b2 >= 0.0f);
        float sd = inside ? -d2 : d2;
        float n0 = b0 * f4.w, n1 = b1 * f5.x, n2 = b2 * f5.y;
        float den = n0 + n1 + n2;
        den = (fabsf(den) < 1e-10f) ? 1e-10f : den;
        float iden = frcp(den);
        float c0 = fmaxf(n0 * iden, 0.0f);
        float c1 = fmaxf(n1 * iden, 0.0f);
        float c2 = fmaxf(n2 * iden, 0.0f);
        float iscn = frcp(fmaxf(c0 + c1 + c2, 1e-10f));
        float bc0 = c0 * iscn, bc1 = c1 * iscn, bc2 = c2 * iscn;
        float u = bc0 * f5.z + bc1 * f6.x + bc2 * f6.z;
        float v = bc0 * f5.w + bc1 * f6.y + bc2 * f6.w;
        float tx = u * 127.0f;
        float ty = (1.0f - v) * 127.0f;
        float x0f = fminf(fmaxf(floorf(tx), 0.0f), 127.0f);
        float y0f = fminf(fmaxf(floorf(ty), 0.0f), 127.0f);
        int x0 = (int)x0f, y0 = (int)y0f;
        int x1 = (x0 + 1 < 127) ? x0 + 1 : 127;
        int y1 = (y0 + 1 < 127) ? y0 + 1 : 127;
        float wx = tx - x0f, wy = ty - y0f;
        const float* t00 = texd + (y0 * 128 + x0) * 3;
        const float* t01 = texd + (y0 * 128 + x1) * 3;
        const float* t10 = texd + (y1 * 128 + x0) * 3;
        const float* t11 = texd + (y1 * 128 + x1) * 3;
        float r  = (1.0f - wy) * ((1.0f - wx) * t00[0] + wx * t01[0]) + wy * ((1.0f - wx) * t10[0] + wx * t11[0]);
        float gc = (1.0f - wy) * ((1.0f - wx) * t00[1] + wx * t01[1]) + wy * ((1.0f - wx) * t10[1] + wx * t11[1]);
        float bc = (1.0f - wy) * ((1.0f - wx) * t00[2] + wx * t01[2]) + wy * ((1.0f - wx) * t10[2] + wx * t11[2]);
        float prob = frcp(1.0f + __expf(sd * 1e4f));  // sigmoid(-sd/SIGMA)
        float zi = (100.0f - zk) * (1.0f / 99.0f);
        float wgt = prob * __expf((zi - zmx) * 1e4f);
        pS = wgt; pR = wgt * r; pG = wgt * gc; pB = wgt * bc; pD = wgt * zk;
        pO = 1.0f - prob;
    }

    // ---------------- Phase 6: intra-group reduce + store ------------------
#pragma unroll
    for (int m = 1; m < 8; m <<= 1) {
        pS += __shfl_xor(pS, m, 8);
        pR += __shfl_xor(pR, m, 8);
        pG += __shfl_xor(pG, m, 8);
        pB += __shfl_xor(pB, m, 8);
        pD += __shfl_xor(pD, m, 8);
        pO *= __shfl_xor(pO, m, 8);
    }
    float delta = __expf((1e-10f - zmx) * 1e4f);
    float S = pS + delta;
    float invS = frcp(S);
    float v0 = pR * invS;
    float v1 = pG * invS;
    float v2 = pB * invS;
    float v3 = 1.0f - pO;
    float v4 = (pD + delta * 100.0f) * invS;  // Z_BACKGROUND
    float val = v0;
    val = (l == 1) ? v1 : val;
    val = (l == 2) ? v2 : val;
    val = (l == 3) ? v3 : val;
    val = (l == 4) ? v4 : val;
    const int o = (y * 128 + x) * 5;
    if (l < 5) out[o + l] = val;
}

extern "C" void kernel_launch(void* const* d_in, const int* in_sizes, int n_in,
                              void* d_out, int out_size, void* d_ws, size_t ws_size,
                              hipStream_t stream) {
    const float* xy_off = (const float*)d_in[0];
    const float* zg     = (const float*)d_in[1];
    const float* rgb    = (const float*)d_in[2];
    const float* R_in   = (const float*)d_in[3];
    const float* T_in   = (const float*)d_in[4];
    const float* R_out  = (const float*)d_in[5];
    const float* T_out  = (const float*)d_in[6];
    float* out = (float*)d_out;
    nvp_kernel<<<dim3(256), dim3(512), 0, stream>>>(xy_off, zg, rgb, R_in, T_in,
                                                    R_out, T_out, out);
}